// Round 16
// baseline (240.450 us; speedup 1.0000x reference)
//
#include <hip/hip_runtime.h>
#include <hip/hip_bf16.h>

// GraphLinear: out[b,n,o] = sum_m g[n,m] * (sum_i input[b,m,i]*W[type[m],o,i]) + bias[o]
// B=16384, N=128, DIN=DOUT=64, T=16.
// R16 = R15 (236.8us) with ONE change: DMA stage depth 1 -> 2 (3-deep ibuf rotation).
//   Chunk c: STAGE(L_{c+2}) at TOP | PHASE1(c) | PHASE2(c-1) [S_c] | BAR(8).
//   Ordered retirement: at BAR(8) the 8 newest (L_{c+2}, S_c) stay in flight, the
//   oldest (L_{c+1}, S_{c-1}) are retired -> per-CU read pipe never empties
//   (64 KB reads outstanding vs 32 KB at depth 1). R14 tested depth 2 with
//   stage-at-end + 2 barriers (confounded); this isolates depth alone.

#define NN   128
#define DI   64
#define DOUT 64
#define TT   16
#define NG   24   // compile-time padded group count (max Sum ceil(n_t/16) = 23)
#define NCH  32   // b-rows per persistent block
#define RSZ  (NN * DI)

typedef __attribute__((ext_vector_type(4))) float f32x4;
typedef __attribute__((ext_vector_type(8))) short bf16x8;

__device__ __forceinline__ short f2bf(float f) {
    return __builtin_bit_cast(short, __float2bfloat16(f));
}

__device__ __forceinline__ bf16x8 cvt8(f32x4 a, f32x4 b) {
    bf16x8 r;
    r[0] = f2bf(a[0]); r[1] = f2bf(a[1]); r[2] = f2bf(a[2]); r[3] = f2bf(a[3]);
    r[4] = f2bf(b[0]); r[5] = f2bf(b[1]); r[6] = f2bf(b[2]); r[7] = f2bf(b[3]);
    return r;
}

__device__ __forceinline__ void load_lds16(const float* gp, float* lp) {
    __builtin_amdgcn_global_load_lds(
        (const __attribute__((address_space(1))) unsigned int*)gp,
        (__attribute__((address_space(3))) unsigned int*)lp, 16, 0, 0);
}

// counted barrier: explicit waitcnt + raw s_barrier (R14/R15-proven machinery)
#define BAR(N) do { \
    asm volatile("s_waitcnt vmcnt(" #N ") lgkmcnt(0)" ::: "memory"); \
    __builtin_amdgcn_s_barrier(); } while (0)

// Device-global scratch (rewritten every launch by prep_kernel; deterministic).
__device__ short d_wb[TT * DOUT * DI];   // bf16 weight [t][o][i], 128 KB
__device__ short d_gb[NN * NN];          // bf16 g [n][m], 32 KB
__device__ int   d_gp[NG * 8];           // per group: m-bytes [0..3], type [4] (-1 = pad)

__global__ void prep_kernel(const float* __restrict__ weight,
                            const float* __restrict__ g,
                            const int*   __restrict__ ntype) {
    const int tid    = blockIdx.x * blockDim.x + threadIdx.x;
    const int stride = gridDim.x * blockDim.x;
    for (int i = tid; i < TT * DOUT * DI; i += stride) d_wb[i] = f2bf(weight[i]);
    for (int i = tid; i < NN * NN; i += stride)        d_gb[i] = f2bf(g[i]);

    if (blockIdx.x == 0) {
        __shared__ int sh_t[NN];
        const int lt = threadIdx.x;
        if (lt < NN) sh_t[lt] = ntype[lt];
        __syncthreads();
        if (lt < TT) {   // lanes 0..15 of wave 0, one type each
            int cnt = 0, m0 = 0;
            for (int m = NN - 1; m >= 0; --m)
                if (sh_t[m] == lt) { ++cnt; m0 = m; }
            const int ng = (cnt + 15) >> 4;
            int pfx = 0, total = 0;
            for (int t2 = 0; t2 < TT; ++t2) {
                const int v = __shfl(ng, t2, 64);
                if (t2 < lt) pfx += v;
                total += v;
            }
            // emit groups of 16; fill bytes = m0 (idempotent duplicate writes)
            const int fill = m0 * 0x01010101;
            int Gw = pfx, cur = 0;
            int pk[4] = {fill, fill, fill, fill};
            for (int m = 0; m < NN; ++m) {
                if (sh_t[m] == lt) {
                    const int w2 = cur >> 2, s8 = (cur & 3) * 8;
                    pk[w2] = (pk[w2] & ~(0xFF << s8)) | (m << s8);
                    if (++cur == 16) {
                        for (int k2 = 0; k2 < 4; ++k2) d_gp[Gw * 8 + k2] = pk[k2];
                        d_gp[Gw * 8 + 4] = lt;
                        ++Gw; cur = 0;
                        for (int k2 = 0; k2 < 4; ++k2) pk[k2] = fill;
                    }
                }
            }
            if (cur > 0) {
                for (int k2 = 0; k2 < 4; ++k2) d_gp[Gw * 8 + k2] = pk[k2];
                d_gp[Gw * 8 + 4] = lt;
                ++Gw;
            }
            // tail pad groups: type = -1 -> main kernel SKIPS them entirely
            if (lt == 0) {
                for (int gp2 = total; gp2 < NG; ++gp2) {
                    for (int k2 = 0; k2 < 4; ++k2) d_gp[gp2 * 8 + k2] = 0;
                    d_gp[gp2 * 8 + 4] = -1;
                }
            }
        }
    }
}

__global__ __launch_bounds__(512, 2)
void graph_linear_main(const float* __restrict__ input,   // [B,128,64] f32
                       const float* __restrict__ bias,    // [64] f32
                       float* __restrict__ out)           // [B,128,64] f32
{
    // ibuf[k] holds b-row r with r%3==k; LDS 16B-unit U holds global unit (U&15)^(m&15).
    // hbuf: [o][m ^ ((o&7)<<3)] bf16, double-buffered. 128 KiB total.
    __shared__ float ibuf0[RSZ];         // 32 KiB
    __shared__ float ibuf1[RSZ];         // 32 KiB
    __shared__ float ibuf2[RSZ];         // 32 KiB
    __shared__ short hbuf0[DOUT * NN];   // 16 KiB
    __shared__ short hbuf1[DOUT * NN];   // 16 KiB

    const int tid  = threadIdx.x;
    const int lane = tid & 63;
    const int wave = tid >> 6;        // 0..7
    const int lo   = lane & 15;
    const int hi   = lane >> 4;       // 0..3
    const size_t bbase = (size_t)blockIdx.x * NCH;
    const float* const inblk = input + bbase * RSZ;

    // ======== block-start hoists (the ONLY global reads besides DMA/stores) ========
    const int wu = __builtin_amdgcn_readfirstlane(wave);
    int mp[NG / 8][5];
#pragma unroll
    for (int it = 0; it < NG / 8; ++it) {
        const int gb = (it * 8 + wu) * 8;
#pragma unroll
        for (int k2 = 0; k2 < 5; ++k2) mp[it][k2] = d_gp[gb + k2];
    }
    bf16x8 wfr[NG / 8][8];   // 96 VGPR, loaded once
#pragma unroll
    for (int it = 0; it < NG / 8; ++it) {
        const int t = (mp[it][4] < 0) ? 0 : mp[it][4];
        const short* wrow = d_wb + t * (DOUT * DI);
#pragma unroll
        for (int ot = 0; ot < 4; ++ot) {
            wfr[it][2 * ot]     = *(const bf16x8*)(wrow + (ot * 16 + lo) * DI + hi * 8);
            wfr[it][2 * ot + 1] = *(const bf16x8*)(wrow + (ot * 16 + lo) * DI + 32 + hi * 8);
        }
    }
    const int n2 = wave * 16 + lo;
    bf16x8 gfr[4];
#pragma unroll
    for (int cc = 0; cc < 4; ++cc)
        gfr[cc] = *(const bf16x8*)(d_gb + n2 * NN + cc * 32 + hi * 8);
    f32x4 bvv[4];
#pragma unroll
    for (int ot = 0; ot < 4; ++ot)
        bvv[ot] = *(const f32x4*)(bias + ot * 16 + hi * 4);

    // ======== helpers ========
    auto STAGE = [&](float* dst, const float* srcrow) {   // 4 global_load_lds / wave
#pragma unroll
        for (int q = 0; q < 4; ++q) {
            const int ck = wave * 4 + q;
            const int U  = ck * 64 + lane;
            const int m  = U >> 4;
            const int u  = (U & 15) ^ (m & 15);
            load_lds16(srcrow + m * 64 + u * 4, dst + ck * 256);
        }
    };
    auto PHASE1 = [&](const float* ib, short* hb) {       // LDS + MFMA only
#pragma unroll
        for (int it = 0; it < NG / 8; ++it) {
            if (mp[it][4] < 0) continue;   // pad group: skip (wave-uniform branch)
            const int p0 = mp[it][0], p1 = mp[it][1];
            const int p2 = mp[it][2], p3 = mp[it][3];
            const int ps = (lo < 8) ? ((lo < 4) ? p0 : p1) : ((lo < 12) ? p2 : p3);
            const int mA = (ps >> ((lo & 3) * 8)) & 0xFF;
            const int sA = mA & 15;
            const float* arow = ib + mA * DI;
            const f32x4 r0 = *(const f32x4*)&arow[((hi * 2)     ^ sA) * 4];
            const f32x4 r1 = *(const f32x4*)&arow[((hi * 2 + 1) ^ sA) * 4];
            const f32x4 r2 = *(const f32x4*)&arow[((hi * 2 + 8) ^ sA) * 4];
            const f32x4 r3 = *(const f32x4*)&arow[((hi * 2 + 9) ^ sA) * 4];
            const bf16x8 a0 = cvt8(r0, r1);           // k = 0..31
            const bf16x8 a1 = cvt8(r2, r3);           // k = 32..63

            f32x4 hacc[4];
#pragma unroll
            for (int ot = 0; ot < 4; ++ot) hacc[ot] = 0.0f;
#pragma unroll
            for (int ot = 0; ot < 4; ++ot) {
                hacc[ot] = __builtin_amdgcn_mfma_f32_16x16x32_bf16(a0, wfr[it][2 * ot],     hacc[ot], 0, 0, 0);
                hacc[ot] = __builtin_amdgcn_mfma_f32_16x16x32_bf16(a1, wfr[it][2 * ot + 1], hacc[ot], 0, 0, 0);
            }
            const int pst = (hi < 2) ? ((hi == 0) ? p0 : p1) : ((hi == 2) ? p2 : p3);
#pragma unroll
            for (int ot = 0; ot < 4; ++ot) {
                const int o   = ot * 16 + lo;
                const int swz = (o & 7) << 3;
#pragma unroll
                for (int j = 0; j < 4; ++j) {
                    const int mS = (pst >> (8 * j)) & 0xFF;
                    hb[o * NN + (mS ^ swz)] = f2bf(hacc[ot][j]);
                }
            }
        }
    };
    auto PHASE2 = [&](const short* hb, float* orow) {     // 4 global stores / wave
        f32x4 acc[4];
#pragma unroll
        for (int ot = 0; ot < 4; ++ot) acc[ot] = bvv[ot];
#pragma unroll
        for (int cc = 0; cc < 4; ++cc) {
#pragma unroll
            for (int ot = 0; ot < 4; ++ot) {
                const int o   = ot * 16 + lo;
                const int pos = (cc * 32 + hi * 8) ^ ((o & 7) << 3);
                const bf16x8 hfr = *(const bf16x8*)&hb[o * NN + pos];
                acc[ot] = __builtin_amdgcn_mfma_f32_16x16x32_bf16(hfr, gfr[cc], acc[ot], 0, 0, 0);
            }
        }
#pragma unroll
        for (int ot = 0; ot < 4; ++ot)
            *(f32x4*)&orow[ot * 16 + hi * 4] = acc[ot];
    };

    // ======== depth-2 counted-vmcnt pipeline (stage at top, one barrier/chunk) ========
    STAGE(ibuf0, inblk);                    // L_0
    STAGE(ibuf1, inblk + RSZ);              // L_1
    BAR(4);                                 // L_0 landed (newer: L_1)

    // ---- chunk 0 (no phase2) ----
    STAGE(ibuf2, inblk + 2 * RSZ);          // L_2
    PHASE1(ibuf0, hbuf0);
    BAR(4);                                 // L_1 landed (newer: L_2)

    // ---- steady chunks 1..NCH-1 ----
#pragma unroll 1
    for (int c = 1; c < NCH; ++c) {
        const int kr = c % 3;
        const int kw = (c + 2) % 3;
        const float* ib = (kr == 0) ? ibuf0 : ((kr == 1) ? ibuf1 : ibuf2);
        float* ibw      = (kw == 0) ? ibuf0 : ((kw == 1) ? ibuf1 : ibuf2);
        const int rr = (c + 2 < NCH) ? (c + 2) : (NCH - 1);   // clamp: dummy, unread buf

        STAGE(ibw, inblk + (size_t)rr * RSZ);                 // L_{c+2} (top)
        PHASE1(ib, (c & 1) ? hbuf1 : hbuf0);
        PHASE2((c & 1) ? hbuf0 : hbuf1,
               out + ((bbase + c - 1) * NN + n2) * DOUT);     // S_c (4 stores)
        BAR(8);   // oldest 8 (L_{c+1}, S_{c-1}) retired; L_{c+2}, S_c stay in flight
    }
    PHASE2(hbuf1, out + ((bbase + NCH - 1) * NN + n2) * DOUT);   // (NCH-1)&1 = 1
}

extern "C" void kernel_launch(void* const* d_in, const int* in_sizes, int n_in,
                              void* d_out, int out_size, void* d_ws, size_t ws_size,
                              hipStream_t stream) {
    const float* input  = (const float*)d_in[0];
    const float* g      = (const float*)d_in[1];
    const float* weight = (const float*)d_in[2];
    const float* bias   = (const float*)d_in[3];
    const int*   ntype  = (const int*)d_in[4];
    float* out = (float*)d_out;

    const int B = in_sizes[0] / RSZ;   // 16384

    hipLaunchKernelGGL(prep_kernel, dim3(128), dim3(256), 0, stream, weight, g, ntype);
    hipLaunchKernelGGL(graph_linear_main, dim3(B / NCH), dim3(512), 0, stream,
                       input, bias, out);
}

// Round 17
// 236.799 us; speedup vs baseline: 1.0154x; 1.0154x over previous
//
#include <hip/hip_runtime.h>
#include <hip/hip_bf16.h>

// GraphLinear: out[b,n,o] = sum_m g[n,m] * (sum_i input[b,m,i]*W[type[m],o,i]) + bias[o]
// B=16384, N=128, DIN=DOUT=64, T=16.
// FINAL (R15, measured best 236.8us = 6.3x baseline):
//   prep: bf16-convert weight/g (128 blocks); groups of 16 same-type m's, NG=24,
//         tail groups marked type=-1 (skipped in main).
//   main: persistent 512 blocks x NCH=32 b-rows; 512 threads (8 waves); 96 KB LDS;
//     launch_bounds(512,2). ALL repeated global reads hoisted to registers once per
//     block (W-frags 96 VGPR, g-frags 16, bias 16, metadata): the chunk loop has
//     ZERO global loads (hipcc serializes any reg-staged global load in a loop -
//     proven R4-R11). Input staged via global_load_lds DMA (no VGPR dest -> cannot
//     be serialized), source pre-swizzled (unit^=m&15) so LDS reads are ~conflict-free.
//     Pipeline per chunk: STAGE(c+1) top | PHASE1(c) | PHASE2(c-1) [4 stores] |
//     s_waitcnt vmcnt(4); s_barrier  -- waits exactly for L_{c+1}, never for stores.
//   Exhausted-null levers (documented so nobody retries them): occupancy 21->67%
//   (null), reg-staged load bursts x6 structures (always serialized, VGPR pinned
//   ~60), counted-vmcnt restructures x3 (null/negative), stage depth 2 (null),
//   pad-group skip (+0), store-drain elimination (+1us).

#define NN   128
#define DI   64
#define DOUT 64
#define TT   16
#define NG   24   // compile-time padded group count (max Sum ceil(n_t/16) = 23)
#define NCH  32   // b-rows per persistent block
#define RSZ  (NN * DI)

typedef __attribute__((ext_vector_type(4))) float f32x4;
typedef __attribute__((ext_vector_type(8))) short bf16x8;

__device__ __forceinline__ short f2bf(float f) {
    return __builtin_bit_cast(short, __float2bfloat16(f));
}

__device__ __forceinline__ bf16x8 cvt8(f32x4 a, f32x4 b) {
    bf16x8 r;
    r[0] = f2bf(a[0]); r[1] = f2bf(a[1]); r[2] = f2bf(a[2]); r[3] = f2bf(a[3]);
    r[4] = f2bf(b[0]); r[5] = f2bf(b[1]); r[6] = f2bf(b[2]); r[7] = f2bf(b[3]);
    return r;
}

__device__ __forceinline__ void load_lds16(const float* gp, float* lp) {
    __builtin_amdgcn_global_load_lds(
        (const __attribute__((address_space(1))) unsigned int*)gp,
        (__attribute__((address_space(3))) unsigned int*)lp, 16, 0, 0);
}

// counted barrier: explicit waitcnt + raw s_barrier
#define BAR(N) do { \
    asm volatile("s_waitcnt vmcnt(" #N ") lgkmcnt(0)" ::: "memory"); \
    __builtin_amdgcn_s_barrier(); } while (0)

// Device-global scratch (rewritten every launch by prep_kernel; deterministic).
__device__ short d_wb[TT * DOUT * DI];   // bf16 weight [t][o][i], 128 KB
__device__ short d_gb[NN * NN];          // bf16 g [n][m], 32 KB
__device__ int   d_gp[NG * 8];           // per group: m-bytes [0..3], type [4] (-1 = pad)

__global__ void prep_kernel(const float* __restrict__ weight,
                            const float* __restrict__ g,
                            const int*   __restrict__ ntype) {
    const int tid    = blockIdx.x * blockDim.x + threadIdx.x;
    const int stride = gridDim.x * blockDim.x;
    for (int i = tid; i < TT * DOUT * DI; i += stride) d_wb[i] = f2bf(weight[i]);
    for (int i = tid; i < NN * NN; i += stride)        d_gb[i] = f2bf(g[i]);

    if (blockIdx.x == 0) {
        __shared__ int sh_t[NN];
        const int lt = threadIdx.x;
        if (lt < NN) sh_t[lt] = ntype[lt];
        __syncthreads();
        if (lt < TT) {   // lanes 0..15 of wave 0, one type each
            int cnt = 0, m0 = 0;
            for (int m = NN - 1; m >= 0; --m)
                if (sh_t[m] == lt) { ++cnt; m0 = m; }
            const int ng = (cnt + 15) >> 4;
            int pfx = 0, total = 0;
            for (int t2 = 0; t2 < TT; ++t2) {
                const int v = __shfl(ng, t2, 64);
                if (t2 < lt) pfx += v;
                total += v;
            }
            // emit groups of 16; fill bytes = m0 (idempotent duplicate writes)
            const int fill = m0 * 0x01010101;
            int Gw = pfx, cur = 0;
            int pk[4] = {fill, fill, fill, fill};
            for (int m = 0; m < NN; ++m) {
                if (sh_t[m] == lt) {
                    const int w2 = cur >> 2, s8 = (cur & 3) * 8;
                    pk[w2] = (pk[w2] & ~(0xFF << s8)) | (m << s8);
                    if (++cur == 16) {
                        for (int k2 = 0; k2 < 4; ++k2) d_gp[Gw * 8 + k2] = pk[k2];
                        d_gp[Gw * 8 + 4] = lt;
                        ++Gw; cur = 0;
                        for (int k2 = 0; k2 < 4; ++k2) pk[k2] = fill;
                    }
                }
            }
            if (cur > 0) {
                for (int k2 = 0; k2 < 4; ++k2) d_gp[Gw * 8 + k2] = pk[k2];
                d_gp[Gw * 8 + 4] = lt;
                ++Gw;
            }
            // tail pad groups: type = -1 -> main kernel SKIPS them entirely
            if (lt == 0) {
                for (int gp2 = total; gp2 < NG; ++gp2) {
                    for (int k2 = 0; k2 < 4; ++k2) d_gp[gp2 * 8 + k2] = 0;
                    d_gp[gp2 * 8 + 4] = -1;
                }
            }
        }
    }
}

__global__ __launch_bounds__(512, 2)
void graph_linear_main(const float* __restrict__ input,   // [B,128,64] f32
                       const float* __restrict__ bias,    // [64] f32
                       float* __restrict__ out)           // [B,128,64] f32
{
    // ibuf: one b-row f32; LDS 16B-unit U holds global unit (U&15)^(m&15) of row m.
    // hbuf: [o][m ^ ((o&7)<<3)] bf16. Both double-buffered. 96 KiB total.
    __shared__ float ibuf0[RSZ];         // 32 KiB
    __shared__ float ibuf1[RSZ];         // 32 KiB
    __shared__ short hbuf0[DOUT * NN];   // 16 KiB
    __shared__ short hbuf1[DOUT * NN];   // 16 KiB

    const int tid  = threadIdx.x;
    const int lane = tid & 63;
    const int wave = tid >> 6;        // 0..7
    const int lo   = lane & 15;
    const int hi   = lane >> 4;       // 0..3
    const size_t bbase = (size_t)blockIdx.x * NCH;
    const float* const inblk = input + bbase * RSZ;

    // ======== block-start hoists (the ONLY global reads besides DMA/stores) ========
    const int wu = __builtin_amdgcn_readfirstlane(wave);
    int mp[NG / 8][5];
#pragma unroll
    for (int it = 0; it < NG / 8; ++it) {
        const int gb = (it * 8 + wu) * 8;
#pragma unroll
        for (int k2 = 0; k2 < 5; ++k2) mp[it][k2] = d_gp[gb + k2];
    }
    bf16x8 wfr[NG / 8][8];   // 96 VGPR, loaded once
#pragma unroll
    for (int it = 0; it < NG / 8; ++it) {
        const int t = (mp[it][4] < 0) ? 0 : mp[it][4];
        const short* wrow = d_wb + t * (DOUT * DI);
#pragma unroll
        for (int ot = 0; ot < 4; ++ot) {
            wfr[it][2 * ot]     = *(const bf16x8*)(wrow + (ot * 16 + lo) * DI + hi * 8);
            wfr[it][2 * ot + 1] = *(const bf16x8*)(wrow + (ot * 16 + lo) * DI + 32 + hi * 8);
        }
    }
    const int n2 = wave * 16 + lo;
    bf16x8 gfr[4];
#pragma unroll
    for (int cc = 0; cc < 4; ++cc)
        gfr[cc] = *(const bf16x8*)(d_gb + n2 * NN + cc * 32 + hi * 8);
    f32x4 bvv[4];
#pragma unroll
    for (int ot = 0; ot < 4; ++ot)
        bvv[ot] = *(const f32x4*)(bias + ot * 16 + hi * 4);

    // ======== helpers ========
    auto STAGE = [&](float* dst, const float* srcrow) {   // 4 global_load_lds / wave
#pragma unroll
        for (int q = 0; q < 4; ++q) {
            const int ck = wave * 4 + q;
            const int U  = ck * 64 + lane;
            const int m  = U >> 4;
            const int u  = (U & 15) ^ (m & 15);
            load_lds16(srcrow + m * 64 + u * 4, dst + ck * 256);
        }
    };
    auto PHASE1 = [&](const float* ib, short* hb) {       // LDS + MFMA only
#pragma unroll
        for (int it = 0; it < NG / 8; ++it) {
            if (mp[it][4] < 0) continue;   // pad group: skip (wave-uniform branch)
            const int p0 = mp[it][0], p1 = mp[it][1];
            const int p2 = mp[it][2], p3 = mp[it][3];
            const int ps = (lo < 8) ? ((lo < 4) ? p0 : p1) : ((lo < 12) ? p2 : p3);
            const int mA = (ps >> ((lo & 3) * 8)) & 0xFF;
            const int sA = mA & 15;
            const float* arow = ib + mA * DI;
            const f32x4 r0 = *(const f32x4*)&arow[((hi * 2)     ^ sA) * 4];
            const f32x4 r1 = *(const f32x4*)&arow[((hi * 2 + 1) ^ sA) * 4];
            const f32x4 r2 = *(const f32x4*)&arow[((hi * 2 + 8) ^ sA) * 4];
            const f32x4 r3 = *(const f32x4*)&arow[((hi * 2 + 9) ^ sA) * 4];
            const bf16x8 a0 = cvt8(r0, r1);           // k = 0..31
            const bf16x8 a1 = cvt8(r2, r3);           // k = 32..63

            f32x4 hacc[4];
#pragma unroll
            for (int ot = 0; ot < 4; ++ot) hacc[ot] = 0.0f;
#pragma unroll
            for (int ot = 0; ot < 4; ++ot) {
                hacc[ot] = __builtin_amdgcn_mfma_f32_16x16x32_bf16(a0, wfr[it][2 * ot],     hacc[ot], 0, 0, 0);
                hacc[ot] = __builtin_amdgcn_mfma_f32_16x16x32_bf16(a1, wfr[it][2 * ot + 1], hacc[ot], 0, 0, 0);
            }
            const int pst = (hi < 2) ? ((hi == 0) ? p0 : p1) : ((hi == 2) ? p2 : p3);
#pragma unroll
            for (int ot = 0; ot < 4; ++ot) {
                const int o   = ot * 16 + lo;
                const int swz = (o & 7) << 3;
#pragma unroll
                for (int j = 0; j < 4; ++j) {
                    const int mS = (pst >> (8 * j)) & 0xFF;
                    hb[o * NN + (mS ^ swz)] = f2bf(hacc[ot][j]);
                }
            }
        }
    };
    auto PHASE2 = [&](const short* hb, float* orow) {     // 4 global stores / wave
        f32x4 acc[4];
#pragma unroll
        for (int ot = 0; ot < 4; ++ot) acc[ot] = bvv[ot];
#pragma unroll
        for (int cc = 0; cc < 4; ++cc) {
#pragma unroll
            for (int ot = 0; ot < 4; ++ot) {
                const int o   = ot * 16 + lo;
                const int pos = (cc * 32 + hi * 8) ^ ((o & 7) << 3);
                const bf16x8 hfr = *(const bf16x8*)&hb[o * NN + pos];
                acc[ot] = __builtin_amdgcn_mfma_f32_16x16x32_bf16(hfr, gfr[cc], acc[ot], 0, 0, 0);
            }
        }
#pragma unroll
        for (int ot = 0; ot < 4; ++ot)
            *(f32x4*)&orow[ot * 16 + hi * 4] = acc[ot];
    };

    // ======== pipeline: stage-at-top, one counted barrier per chunk ========
    STAGE(ibuf0, inblk);                    // L_0
    STAGE(ibuf1, inblk + RSZ);              // L_1
    BAR(4);                                 // L_0 landed (newer: L_1)

    // ---- chunk 0 (no phase2) ----
    PHASE1(ibuf0, hbuf0);
    BAR(0);                                 // L_1 landed (nothing newer outstanding)

    // ---- steady chunks 1..NCH-1 ----
#pragma unroll 1
    for (int c = 1; c < NCH; ++c) {
        if (c + 1 < NCH)
            STAGE((c & 1) ? ibuf0 : ibuf1, inblk + (size_t)(c + 1) * RSZ);   // L_{c+1}
        PHASE1((c & 1) ? ibuf1 : ibuf0, (c & 1) ? hbuf1 : hbuf0);
        PHASE2((c & 1) ? hbuf0 : hbuf1,
               out + ((bbase + c - 1) * NN + n2) * DOUT);                    // S_c (4 stores)
        BAR(4);   // L_{c+1} landed; the 4 stores stay in flight (never waited)
    }
    PHASE2(hbuf1, out + ((bbase + NCH - 1) * NN + n2) * DOUT);   // (NCH-1)&1 = 1
}

extern "C" void kernel_launch(void* const* d_in, const int* in_sizes, int n_in,
                              void* d_out, int out_size, void* d_ws, size_t ws_size,
                              hipStream_t stream) {
    const float* input  = (const float*)d_in[0];
    const float* g      = (const float*)d_in[1];
    const float* weight = (const float*)d_in[2];
    const float* bias   = (const float*)d_in[3];
    const int*   ntype  = (const int*)d_in[4];
    float* out = (float*)d_out;

    const int B = in_sizes[0] / RSZ;   // 16384

    hipLaunchKernelGGL(prep_kernel, dim3(128), dim3(256), 0, stream, weight, g, ntype);
    hipLaunchKernelGGL(graph_linear_main, dim3(B / NCH), dim3(512), 0, stream,
                       input, bias, out);
}